// Round 13
// baseline (947.173 us; speedup 1.0000x reference)
//
#include <hip/hip_runtime.h>
#include <math.h>

#define BT 16
#define CCH 256
#define IH 96
#define IW 96
#define HW (IH*IW)            // 9216
#define DK 64

static const long long WIN   = (long long)BT * HW * DK;   // 9,437,184 elems (one head, all bt)
static const long long NFULL = 4 * WIN;                    // 37,748,736 elems
static const long long WB    = WIN * 2;                    // bytes of one bf16 head buffer
#define CHUNKB 39936          // bytes of one conv LDS-image chunk (6*104*32*2)

typedef __attribute__((ext_vector_type(8))) short bf16x8;
typedef __attribute__((ext_vector_type(4))) float f32x4;

__device__ __forceinline__ unsigned short f2bf(float f) {
    unsigned int x = __float_as_uint(f);
    unsigned int r = (x + 0x7FFFu + ((x >> 16) & 1u)) >> 16;
    return (unsigned short)r;
}

__device__ __forceinline__ void async16(void* lds, const void* g) {
    __builtin_amdgcn_global_load_lds(
        (const __attribute__((address_space(1))) unsigned int*)g,
        (__attribute__((address_space(3))) unsigned int*)lds, 16, 0, 0);
}

// ---------------- transpose+convert: x[bt][c][hw] fp32 -> xT[bt][hw][c] bf16
__global__ __launch_bounds__(256) void transpose_cvt_kernel(const float* __restrict__ x,
    unsigned short* __restrict__ xT)
{
    __shared__ float Ls[64][65];
    int tid = threadIdx.x;
    int p0 = blockIdx.x * 64;
    int c0 = blockIdx.y * 64;
    int bt = blockIdx.z;
    int px4 = (tid & 15) * 4, chb = tid >> 4;
    const float* xb = x + ((long long)(bt * CCH + c0) * HW) + p0;
    #pragma unroll
    for (int it = 0; it < 4; it++) {
        int ch = chb + it * 16;
        float4 v = *(const float4*)(xb + (long long)ch * HW + px4);
        Ls[px4 + 0][ch] = v.x;
        Ls[px4 + 1][ch] = v.y;
        Ls[px4 + 2][ch] = v.z;
        Ls[px4 + 3][ch] = v.w;
    }
    __syncthreads();
    int px = tid >> 2, cg = (tid & 3) * 16;
    unsigned short* dst = xT + ((long long)bt * HW + p0 + px) * CCH + c0 + cg;
    #pragma unroll
    for (int half = 0; half < 2; half++) {
        ushort4 a, b;
        a.x = f2bf(Ls[px][cg + half * 8 + 0]);
        a.y = f2bf(Ls[px][cg + half * 8 + 1]);
        a.z = f2bf(Ls[px][cg + half * 8 + 2]);
        a.w = f2bf(Ls[px][cg + half * 8 + 3]);
        b.x = f2bf(Ls[px][cg + half * 8 + 4]);
        b.y = f2bf(Ls[px][cg + half * 8 + 5]);
        b.z = f2bf(Ls[px][cg + half * 8 + 6]);
        b.w = f2bf(Ls[px][cg + half * 8 + 7]);
        *(ushort4*)(dst + half * 8)     = a;
        *(ushort4*)(dst + half * 8 + 4) = b;
    }
}

// ---------------- Wq/Wk/Wv fp32 -> bf16 (same [o][c] layout), packed [3][256][256]
__global__ __launch_bounds__(256) void cvtw_kernel(const float* __restrict__ Wq,
    const float* __restrict__ Wk, const float* __restrict__ Wv,
    unsigned short* __restrict__ Wb)
{
    int idx = blockIdx.x * 256 + threadIdx.x;
    if (idx >= 3 * 16384) return;
    const float* src = idx < 16384 ? Wq : (idx < 32768 ? Wk : Wv);
    int off = (idx & 16383) * 4;
    float4 v = *(const float4*)(src + off);
    ushort4 u = {f2bf(v.x), f2bf(v.y), f2bf(v.z), f2bf(v.w)};
    *(ushort4*)(Wb + (long long)idx * 4) = u;
}

// ---------------- fused 1x1-conv projections via bf16 MFMA (bf16 inputs)
template<int NPASS>
__global__ __launch_bounds__(256) void proj_mfma_kernel(
    const unsigned short* __restrict__ xT,
    const unsigned short* __restrict__ Wb0, const float* __restrict__ b0, unsigned short* __restrict__ o0p,
    const unsigned short* __restrict__ Wb1, const float* __restrict__ b1, unsigned short* __restrict__ o1p,
    unsigned short* __restrict__ i0p, unsigned short* __restrict__ i1p)
{
    __shared__ alignas(16) unsigned short Xs[64 * 256];
    __shared__ alignas(16) unsigned short Ws[256 * 64];
    int tid = threadIdx.x;
    int p0 = blockIdx.x * 64;
    int bt = blockIdx.z;
    int w = tid >> 6, l = tid & 63, l15 = l & 15, lg = l >> 4;

    {
        const unsigned short* xb = xT + ((long long)bt * HW + p0) * CCH;
        #pragma unroll
        for (int it = 0; it < 8; it++) {
            int flat = tid + it * 256;
            int px = flat >> 5, cg = flat & 31;
            bf16x8 v = *(const bf16x8*)(xb + (long long)px * CCH + cg * 8);
            *(bf16x8*)((char*)Xs + px * 512 + ((cg ^ (px & 31)) << 4)) = v;
        }
    }

    for (int pass = 0; pass < NPASS; pass++) {
        const unsigned short* W = pass ? Wb1 : Wb0;
        const float* bias = pass ? b1 : b0;
        unsigned short* outp = pass ? o1p : o0p;
        unsigned short* img = pass ? i1p : i0p;

        f32x4 acc[4][4];
        #pragma unroll
        for (int i = 0; i < 4; i++)
            #pragma unroll
            for (int j = 0; j < 4; j++) acc[i][j] = (f32x4){0.f, 0.f, 0.f, 0.f};

        for (int kc = 0; kc < CCH; kc += 64) {
            __syncthreads();
            #pragma unroll
            for (int it = 0; it < 8; it++) {
                int flat = tid + it * 256;
                int o = flat >> 3, kg = flat & 7;
                bf16x8 v = *(const bf16x8*)(W + o * 256 + kc + kg * 8);
                *(bf16x8*)((char*)Ws + o * 128 + ((kg ^ (o & 7)) << 4)) = v;
            }
            __syncthreads();
            #pragma unroll
            for (int kst = 0; kst < 2; kst++) {
                bf16x8 a[4], b[4];
                #pragma unroll
                for (int mf = 0; mf < 4; mf++) {
                    int m = w * 64 + mf * 16 + l15;
                    int uu = (kst * 4 + lg) ^ (m & 7);
                    a[mf] = *(const bf16x8*)((const char*)Ws + m * 128 + (uu << 4));
                }
                #pragma unroll
                for (int nf = 0; nf < 4; nf++) {
                    int px = nf * 16 + l15;
                    int ug = (kc >> 3) + kst * 4 + lg;
                    b[nf] = *(const bf16x8*)((const char*)Xs + px * 512 + ((ug ^ (px & 31)) << 4));
                }
                #pragma unroll
                for (int mf = 0; mf < 4; mf++)
                    #pragma unroll
                    for (int nf = 0; nf < 4; nf++)
                        acc[mf][nf] = __builtin_amdgcn_mfma_f32_16x16x32_bf16(a[mf], b[nf], acc[mf][nf], 0, 0, 0);
            }
        }

        __syncthreads();
        #pragma unroll
        for (int mf = 0; mf < 4; mf++) {
            int ch0 = w * 64 + mf * 16 + lg * 4;
            float4 bv = *(const float4*)(bias + ch0);
            #pragma unroll
            for (int nf = 0; nf < 4; nf++) {
                int px = nf * 16 + l15;
                ushort4 u4 = {f2bf(acc[mf][nf][0] + bv.x), f2bf(acc[mf][nf][1] + bv.y),
                              f2bf(acc[mf][nf][2] + bv.z), f2bf(acc[mf][nf][3] + bv.w)};
                int uu = (ch0 >> 3) ^ (px & 31);
                *(ushort4*)((char*)Ws + px * 512 + (uu << 4) + ((ch0 >> 2) & 1) * 8) = u4;
            }
        }
        __syncthreads();
        {
            int cg = tid & 31;
            int h = cg >> 3, lp = h + 1, P = 2 << h;
            int side = 96 >> lp;
            int nwin = side * side;
            long long dlen = (long long)64 << (2 * lp);
            unsigned short* dst = outp + (long long)h * WIN + (long long)bt * nwin * dlen + (cg & 7) * 8;
            #pragma unroll
            for (int it = 0; it < 8; it++) {
                int pxl = it * 8 + (tid >> 5);
                int p = p0 + pxl;
                int y = p / 96, xx = p - y * 96;
                int n = (y >> lp) * side + (xx >> lp);
                int pyx = ((y & (P - 1)) << lp) + (xx & (P - 1));
                int uu = cg ^ (pxl & 31);
                bf16x8 v = *(const bf16x8*)((const char*)Ws + pxl * 512 + (uu << 4));
                if (img != nullptr && h == 0) {
                    int mt = n >> 6, row = n & 63;
                    int kg = pyx * 8 + (cg & 7);
                    int u = (kg & 24) | ((kg ^ row) & 7);
                    *(bf16x8*)((char*)img + (((long long)(bt * 36 + mt)) << 15) + row * 512 + (u << 4)) = v;
                } else {
                    *(bf16x8*)(dst + (long long)n * dlen + (long long)pyx * 64) = v;
                }
            }
        }
    }
}

// ---------------- head0 V -> V^T LDS-image tiles in global
__global__ __launch_bounds__(256) void v_image_kernel(
    const unsigned short* __restrict__ vf, unsigned short* __restrict__ vimg)
{
    __shared__ alignas(16) unsigned short Vt[64 * 256];
    int tid = threadIdx.x;
    int mt = blockIdx.x;   // 0..35
    int bt = blockIdx.y;
    const unsigned short* vb = vf + ((long long)bt * 2304 + mt * 64) * 256;
    unsigned short* vi = vimg + (long long)(bt * 36 + mt) * (64 * 256);

    int du = tid & 15, mu = tid >> 4;
    #pragma unroll
    for (int dblk = 0; dblk < 4; dblk++) {
        ushort4 vv[4];
        #pragma unroll
        for (int i = 0; i < 4; i++)
            vv[i] = *(const ushort4*)(vb + (long long)(mu * 4 + i) * 256 + (dblk * 16 + du) * 4);
        #pragma unroll
        for (int j = 0; j < 4; j++) {
            int d = (dblk * 16 + du) * 4 + j;
            ushort4 tj;
            tj.x = ((const unsigned short*)&vv[0])[j];
            tj.y = ((const unsigned short*)&vv[1])[j];
            tj.z = ((const unsigned short*)&vv[2])[j];
            tj.w = ((const unsigned short*)&vv[3])[j];
            int slot = (((mu >> 3) * 4 + (mu & 3)) ^ (d & 7));
            *(ushort4*)((char*)Vt + d * 128 + (slot << 4) + ((mu & 4) ? 8 : 0)) = tj;
        }
    }
    __syncthreads();
    #pragma unroll
    for (int it = 0; it < 8; it++) {
        int c = tid + it * 256;
        *(bf16x8*)((char*)vi + c * 16) = *(const bf16x8*)((const char*)Vt + c * 16);
    }
}

// ---------------- head 0 flash attention: 256 thr / 4 waves, 2 q-sets per wave
// QBLK=128; each K/V^T LDS read feeds TWO MFMAs (sets A and B) -> 0.5 reads/MFMA.
__global__ __launch_bounds__(256, 1) void flash0_kernel(
    const unsigned short* __restrict__ q, const unsigned short* __restrict__ kimg,
    const unsigned short* __restrict__ vimg, unsigned short* __restrict__ o)
{
    constexpr int NW = 2304, D = 256;
    __shared__ alignas(16) unsigned short Kb[64 * 256];   // 32KB K tile image
    __shared__ alignas(16) unsigned short Vb[64 * 256];   // 32KB V^T tile image
    int tid = threadIdx.x;
    int w = tid >> 6, l = tid & 63, l15 = l & 15, lg = l >> 4;
    int bid = blockIdx.x;
    int xcd = bid & 7, r = bid >> 3;          // bt<->XCD binding for L2 locality
    int bt = 2 * xcd + (r >= 18 ? 1 : 0);
    int qt = (r >= 18) ? r - 18 : r;
    int q0 = qt * 128;
    const unsigned short* qb = q + ((long long)bt * NW + q0) * D;
    const char* kti = (const char*)(kimg + (long long)bt * 36 * (64 * 256));
    const char* vti = (const char*)(vimg + (long long)bt * 36 * (64 * 256));
    const float scale = 1.0f / 16.0f;

    // Q fragments for both sets (B operand: col = q)
    bf16x8 qfA[8], qfB[8];
    #pragma unroll
    for (int i = 0; i < 8; i++) {
        qfA[i] = *(const bf16x8*)(qb + (long long)(w * 32 + l15) * D + i * 32 + lg * 8);
        qfB[i] = *(const bf16x8*)(qb + (long long)(w * 32 + 16 + l15) * D + i * 32 + lg * 8);
    }

    f32x4 OA[16], OB[16];
    #pragma unroll
    for (int i = 0; i < 16; i++) {
        OA[i] = (f32x4){0.f, 0.f, 0.f, 0.f};
        OB[i] = (f32x4){0.f, 0.f, 0.f, 0.f};
    }
    float mA = -3e38f, sA = 0.f, mB = -3e38f, sB = 0.f;

    int lanebyte = tid * 16;
    int wavebyte = w * 1024;

    for (int mt = 0; mt < 36; mt++) {
        __syncthreads();
        const char* ks = kti + (long long)mt * 32768;
        const char* vs = vti + (long long)mt * 32768;
        #pragma unroll
        for (int i = 0; i < 8; i++) {
            async16((char*)Kb + i * 4096 + wavebyte, ks + i * 4096 + lanebyte);
            async16((char*)Vb + i * 4096 + wavebyte, vs + i * 4096 + lanebyte);
        }
        __syncthreads();
        // ---- swapped QK^T for both sets: one K read -> 2 MFMAs
        f32x4 scA[4], scB[4];
        #pragma unroll
        for (int nf = 0; nf < 4; nf++) {
            scA[nf] = (f32x4){0.f, 0.f, 0.f, 0.f};
            scB[nf] = (f32x4){0.f, 0.f, 0.f, 0.f};
        }
        #pragma unroll
        for (int i = 0; i < 8; i++) {
            int kgu = i * 4 + lg;
            #pragma unroll
            for (int nf = 0; nf < 4; nf++) {
                int arow = nf * 16 + l15;
                int u = (kgu & 24) | ((kgu ^ arow) & 7);
                bf16x8 a = *(const bf16x8*)((const char*)Kb + arow * 512 + (u << 4));
                scA[nf] = __builtin_amdgcn_mfma_f32_16x16x32_bf16(a, qfA[i], scA[nf], 0, 0, 0);
                scB[nf] = __builtin_amdgcn_mfma_f32_16x16x32_bf16(a, qfB[i], scB[nf], 0, 0, 0);
            }
        }
        // ---- online softmax per set (per-lane q = l15, replicated over lg)
        float pmA = -3e38f, pmB = -3e38f;
        #pragma unroll
        for (int nf = 0; nf < 4; nf++)
            #pragma unroll
            for (int rg = 0; rg < 4; rg++) {
                scA[nf][rg] *= scale; pmA = fmaxf(pmA, scA[nf][rg]);
                scB[nf][rg] *= scale; pmB = fmaxf(pmB, scB[nf][rg]);
            }
        pmA = fmaxf(pmA, __shfl_xor(pmA, 16, 64));
        pmA = fmaxf(pmA, __shfl_xor(pmA, 32, 64));
        pmB = fmaxf(pmB, __shfl_xor(pmB, 16, 64));
        pmB = fmaxf(pmB, __shfl_xor(pmB, 32, 64));
        if (__any(pmA > mA)) {
            float mnew = fmaxf(mA, pmA);
            float corr = __expf(mA - mnew);
            mA = mnew; sA *= corr;
            float cO[4];
            #pragma unroll
            for (int rg = 0; rg < 4; rg++) cO[rg] = __shfl(corr, (l & 48) | (lg * 4 + rg), 64);
            #pragma unroll
            for (int nf2 = 0; nf2 < 16; nf2++)
                #pragma unroll
                for (int rg = 0; rg < 4; rg++) OA[nf2][rg] *= cO[rg];
        }
        if (__any(pmB > mB)) {
            float mnew = fmaxf(mB, pmB);
            float corr = __expf(mB - mnew);
            mB = mnew; sB *= corr;
            float cO[4];
            #pragma unroll
            for (int rg = 0; rg < 4; rg++) cO[rg] = __shfl(corr, (l & 48) | (lg * 4 + rg), 64);
            #pragma unroll
            for (int nf2 = 0; nf2 < 16; nf2++)
                #pragma unroll
                for (int rg = 0; rg < 4; rg++) OB[nf2][rg] *= cO[rg];
        }
        float psA = 0.f, psB = 0.f;
        #pragma unroll
        for (int nf = 0; nf < 4; nf++)
            #pragma unroll
            for (int rg = 0; rg < 4; rg++) {
                scA[nf][rg] = __expf(scA[nf][rg] - mA); psA += scA[nf][rg];
                scB[nf][rg] = __expf(scB[nf][rg] - mB); psB += scB[nf][rg];
            }
        psA += __shfl_xor(psA, 16, 64);
        psA += __shfl_xor(psA, 32, 64);
        psB += __shfl_xor(psB, 16, 64);
        psB += __shfl_xor(psB, 32, 64);
        sA += psA; sB += psB;
        // pack P into A fragments (sigma layout matching vimg)
        bf16x8 paA[2], paB[2];
        #pragma unroll
        for (int sl = 0; sl < 2; sl++) {
            paA[sl][0] = (short)f2bf(scA[sl * 2][0]);
            paA[sl][1] = (short)f2bf(scA[sl * 2][1]);
            paA[sl][2] = (short)f2bf(scA[sl * 2][2]);
            paA[sl][3] = (short)f2bf(scA[sl * 2][3]);
            paA[sl][4] = (short)f2bf(scA[sl * 2 + 1][0]);
            paA[sl][5] = (short)f2bf(scA[sl * 2 + 1][1]);
            paA[sl][6] = (short)f2bf(scA[sl * 2 + 1][2]);
            paA[sl][7] = (short)f2bf(scA[sl * 2 + 1][3]);
            paB[sl][0] = (short)f2bf(scB[sl * 2][0]);
            paB[sl][1] = (short)f2bf(scB[sl * 2][1]);
            paB[sl][2] = (short)f2bf(scB[sl * 2][2]);
            paB[sl][3] = (short)f2bf(scB[sl * 2][3]);
            paB[sl][4] = (short)f2bf(scB[sl * 2 + 1][0]);
            paB[sl][5] = (short)f2bf(scB[sl * 2 + 1][1]);
            paB[sl][6] = (short)f2bf(scB[sl * 2 + 1][2]);
            paB[sl][7] = (short)f2bf(scB[sl * 2 + 1][3]);
        }
        // ---- PV: one V^T read -> 2 MFMAs
        #pragma unroll
        for (int nf2 = 0; nf2 < 16; nf2++) {
            int d = nf2 * 16 + l15;
            #pragma unroll
            for (int kc = 0; kc < 2; kc++) {
                int slot = (kc * 4 + lg) ^ (d & 7);
                bf16x8 b = *(const bf16x8*)((const char*)Vb + d * 128 + (slot << 4));
                OA[nf2] = __builtin_amdgcn_mfma_f32_16x16x32_bf16(paA[kc], b, OA[nf2], 0, 0, 0);
                OB[nf2] = __builtin_amdgcn_mfma_f32_16x16x32_bf16(paB[kc], b, OB[nf2], 0, 0, 0);
            }
        }
    }
    // ---- epilogue for both sets
    float invA = 1.f / sA, invB = 1.f / sB;
    float iOA[4], iOB[4];
    #pragma unroll
    for (int rg = 0; rg < 4; rg++) {
        iOA[rg] = __shfl(invA, (l & 48) | (lg * 4 + rg), 64);
        iOB[rg] = __shfl(invB, (l & 48) | (lg * 4 + rg), 64);
    }
    unsigned short* ob = o + ((long long)bt * NW + q0) * D;
    #pragma unroll
    for (int rg = 0; rg < 4; rg++) {
        int qrA = w * 32 + lg * 4 + rg;
        #pragma unroll
        for (int nf2 = 0; nf2 < 16; nf2++) {
            int dd = nf2 * 16 + l15;
            ob[(long long)qrA * D + dd] = f2bf(OA[nf2][rg] * iOA[rg]);
            ob[(long long)(qrA + 16) * D + dd] = f2bf(OB[nf2][rg] * iOB[rg]);
        }
    }
}

// ---------------- QK^T via bf16 MFMA, 64x64 tile, optional split-K (heads 1-3)
__global__ __launch_bounds__(256) void qk_mfma_kernel(const unsigned short* __restrict__ qw,
    const unsigned short* __restrict__ kw, float* __restrict__ scores,
    float* __restrict__ partial, int nw, int dlen, float scale, int ksplit,
    int tspan, int bt0)
{
    __shared__ alignas(16) unsigned short Qs[64 * 64];
    __shared__ alignas(16) unsigned short Ks[64 * 64];
    int tid = threadIdx.x;
    int m0 = blockIdx.x * 64, n0 = blockIdx.y * 64;
    int btl = blockIdx.z / ksplit;
    int kidx = blockIdx.z - btl * ksplit;
    int bt = bt0 + btl;
    int dchunk = dlen / ksplit;
    long long kbase = (long long)kidx * dchunk;
    int w = tid >> 6, l = tid & 63, l15 = l & 15, lg = l >> 4;
    f32x4 acc[4];
    #pragma unroll
    for (int nf = 0; nf < 4; nf++) acc[nf] = (f32x4){0.f, 0.f, 0.f, 0.f};

    const unsigned short* qb = qw + ((long long)bt * nw + n0) * dlen + kbase;
    const unsigned short* kb = kw + ((long long)bt * nw + m0) * dlen + kbase;
    int qrows = nw - n0; if (qrows > 64) qrows = 64;
    int krows = nw - m0; if (krows > 64) krows = 64;
    int arow = w * 16 + l15;

    for (int kc = 0; kc < dchunk; kc += 64) {
        if (kc) __syncthreads();
        #pragma unroll
        for (int i = 0; i < 2; i++) {
            int c = tid + i * 256;
            int row = c >> 3, kg = c & 7;
            int kgs = (kg ^ (row & 7)) * 8;
            bf16x8 qv = {0,0,0,0,0,0,0,0};
            bf16x8 kv = {0,0,0,0,0,0,0,0};
            if (row < qrows) qv = *(const bf16x8*)(qb + (long long)row * dlen + kc + kg * 8);
            if (row < krows) kv = *(const bf16x8*)(kb + (long long)row * dlen + kc + kg * 8);
            *(bf16x8*)(Qs + row * 64 + kgs) = qv;
            *(bf16x8*)(Ks + row * 64 + kgs) = kv;
        }
        __syncthreads();
        #pragma unroll
        for (int k0 = 0; k0 < 64; k0 += 32) {
            int kg = (k0 >> 3) + lg;
            bf16x8 a = *(const bf16x8*)(Qs + arow * 64 + (kg ^ (arow & 7)) * 8);
            #pragma unroll
            for (int nf = 0; nf < 4; nf++) {
                int col = nf * 16 + l15;
                bf16x8 b = *(const bf16x8*)(Ks + col * 64 + (kg ^ (col & 7)) * 8);
                acc[nf] = __builtin_amdgcn_mfma_f32_16x16x32_bf16(a, b, acc[nf], 0, 0, 0);
            }
        }
    }

    if (ksplit == 1) {
        #pragma unroll
        for (int nf = 0; nf < 4; nf++) {
            int c = m0 + nf * 16 + l15;
            #pragma unroll
            for (int reg = 0; reg < 4; reg++) {
                int r = n0 + w * 16 + lg * 4 + reg;
                if (r < nw && c < nw)
                    scores[((long long)btl * nw + r) * nw + c] = acc[nf][reg] * scale;
            }
        }
    } else {
        #pragma unroll
        for (int nf = 0; nf < 4; nf++) {
            int c = m0 + nf * 16 + l15;
            #pragma unroll
            for (int reg = 0; reg < 4; reg++) {
                int r = n0 + w * 16 + lg * 4 + reg;
                partial[(((long long)btl * ksplit + kidx) * tspan + r) * tspan + c] = acc[nf][reg];
            }
        }
    }
}

// ---------------- row softmax (with fused split-K reduce): scores/partial in, bf16 P out
__global__ __launch_bounds__(256) void softmax_kernel(const float* __restrict__ scores,
    const float* __restrict__ partial, unsigned short* __restrict__ pb16,
    int nw, int tspan, int ksplit, float scale)
{
    __shared__ float red[8];
    int n = blockIdx.x, btl = blockIdx.y;
    const float* row = scores + ((long long)btl * nw + n) * nw;
    unsigned short* prow = pb16 + ((long long)btl * nw + n) * nw;
    int tid = threadIdx.x;
    float vals[9];
    float lmax = -3e38f;
    #pragma unroll
    for (int it = 0; it < 9; it++) {
        int m = tid + it * 256;
        if (m < nw) {
            float v;
            if (ksplit == 1) {
                v = row[m];
            } else {
                float s = 0.f;
                for (int k = 0; k < ksplit; k++)
                    s += partial[(((long long)btl * ksplit + k) * tspan + n) * tspan + m];
                v = s * scale;
            }
            vals[it] = v; lmax = fmaxf(lmax, v);
        } else vals[it] = -3e38f;
    }
    #pragma unroll
    for (int o = 32; o > 0; o >>= 1) lmax = fmaxf(lmax, __shfl_down(lmax, o, 64));
    if ((tid & 63) == 0) red[tid >> 6] = lmax;
    __syncthreads();
    float rmax = fmaxf(fmaxf(red[0], red[1]), fmaxf(red[2], red[3]));
    __syncthreads();
    float lsum = 0.f;
    #pragma unroll
    for (int it = 0; it < 9; it++) {
        int m = tid + it * 256;
        if (m < nw) { vals[it] = __expf(vals[it] - rmax); lsum += vals[it]; }
    }
    #pragma unroll
    for (int o = 32; o > 0; o >>= 1) lsum += __shfl_down(lsum, o, 64);
    if ((tid & 63) == 0) red[tid >> 6] = lsum;
    __syncthreads();
    float rsum = red[0] + red[1] + red[2] + red[3];
    float inv = 1.f / rsum;
    #pragma unroll
    for (int it = 0; it < 9; it++) {
        int m = tid + it * 256;
        if (m < nw) prow[m] = f2bf(vals[it] * inv);
    }
}

// ---------------- P @ V via bf16 MFMA; 64(n) x 64(d) tile, bf16 output
__global__ __launch_bounds__(256) void pv_mfma_kernel(const unsigned short* __restrict__ p,
    const unsigned short* __restrict__ vw, unsigned short* __restrict__ yw, int nw, int dlen, int bt0)
{
    __shared__ alignas(16) unsigned short Ps[64 * 64];
    __shared__ alignas(16) unsigned short Vt[64 * 64];
    int tid = threadIdx.x;
    int d0 = blockIdx.x * 64, n0 = blockIdx.y * 64;
    int btl = blockIdx.z;
    int bt = bt0 + btl;
    int w = tid >> 6, l = tid & 63, l15 = l & 15, lg = l >> 4;
    f32x4 acc[4];
    #pragma unroll
    for (int nf = 0; nf < 4; nf++) acc[nf] = (f32x4){0.f, 0.f, 0.f, 0.f};

    const unsigned short* pb = p + ((long long)btl * nw + n0) * nw;
    const unsigned short* vb = vw + (long long)bt * nw * dlen + d0;
    int prows = nw - n0; if (prows > 64) prows = 64;
    int arow = w * 16 + l15;
    int du = tid & 15, mu = tid >> 4;

    for (int mc = 0; mc < nw; mc += 64) {
        if (mc) __syncthreads();
        int mrem = nw - mc;
        #pragma unroll
        for (int i = 0; i < 2; i++) {
            int c = tid + i * 256;
            int row = c >> 3, kg = c & 7;
            bf16x8 v = {0,0,0,0,0,0,0,0};
            if (row < prows) {
                int mb = kg * 8;
                if (mb + 8 <= mrem) v = *(const bf16x8*)(pb + (long long)row * nw + mc + mb);
                else if (mb < mrem) {
                    for (int e = 0; e < mrem - mb; e++)
                        v[e] = (short)pb[(long long)row * nw + mc + mb + e];
                }
            }
            *(bf16x8*)(Ps + row * 64 + (kg ^ (row & 7)) * 8) = v;
        }
        {
            ushort4 vv[4];
            #pragma unroll
            for (int i = 0; i < 4; i++) {
                int m = mc + mu * 4 + i;
                if (m < nw) vv[i] = *(const ushort4*)(vb + (long long)m * dlen + du * 4);
                else vv[i] = (ushort4){0, 0, 0, 0};
            }
            #pragma unroll
            for (int j = 0; j < 4; j++) {
                int d = du * 4 + j;
                int byte = d * 128 + (((mu >> 1) ^ (d & 7)) * 16) + (mu & 1) * 8;
                ushort4 tj;
                tj.x = ((const unsigned short*)&vv[0])[j];
                tj.y = ((const unsigned short*)&vv[1])[j];
                tj.z = ((const unsigned short*)&vv[2])[j];
                tj.w = ((const unsigned short*)&vv[3])[j];
                *(ushort4*)((char*)Vt + byte) = tj;
            }
        }
        __syncthreads();
        #pragma unroll
        for (int k0 = 0; k0 < 64; k0 += 32) {
            int kg = (k0 >> 3) + lg;
            bf16x8 a = *(const bf16x8*)(Ps + arow * 64 + (kg ^ (arow & 7)) * 8);
            #pragma unroll
            for (int nf = 0; nf < 4; nf++) {
                int col = nf * 16 + l15;
                bf16x8 b = *(const bf16x8*)(Vt + col * 64 + (kg ^ (col & 7)) * 8);
                acc[nf] = __builtin_amdgcn_mfma_f32_16x16x32_bf16(a, b, acc[nf], 0, 0, 0);
            }
        }
    }

    #pragma unroll
    for (int nf = 0; nf < 4; nf++) {
        int d = d0 + nf * 16 + l15;
        #pragma unroll
        for (int reg = 0; reg < 4; reg++) {
            int n = n0 + w * 16 + lg * 4 + reg;
            if (n < nw)
                yw[((long long)bt * nw + n) * dlen + d] = f2bf(acc[nf][reg]);
        }
    }
}

// ---------------- Wo fp32 [o][c][3][3] -> bf16 Wt[t][cc][o][cl]
__global__ __launch_bounds__(256) void transform_w_kernel(const float* __restrict__ Wo,
    unsigned short* __restrict__ Wt)
{
    int idx = blockIdx.x * 256 + threadIdx.x;
    if (idx >= 9 * 8 * 256 * 32) return;
    int cl = idx & 31;
    int o  = (idx >> 5) & 255;
    int cc = (idx >> 13) & 7;
    int t  = idx >> 16;
    int dy = t / 3, dx = t - dy * 3;
    int c = cc * 32 + cl;
    Wt[idx] = f2bf(Wo[((long long)(o * CCH + c) * 3 + dy) * 3 + dx]);
}

// ---------------- conv input image: per (ytile, cc, bt), byte-exact LDS tile in global
__global__ __launch_bounds__(256) void conv_image_kernel(
    const unsigned short* __restrict__ ywb_all, char* __restrict__ img)
{
    int tid = threadIdx.x;
    int ytile = blockIdx.x, cc = blockIdx.y, bt = blockIdx.z;
    int ybase = ytile * 4;
    char* chunk = img + (size_t)(((bt * 24 + ytile) * 8) + cc) * CHUNKB;
    int h = cc >> 1;
    int lp = h + 1, P = 2 << h;
    int side = 96 >> lp;
    int nwin = side * side;
    long long dlen = 64LL << (2 * lp);
    const unsigned short* yb = ywb_all + (long long)h * WIN
                             + (long long)bt * nwin * dlen + (cc & 1) * 32;
    for (int it = tid; it < 96; it += 256) {
        int sde = it / 48, rem = it - sde * 48;
        int row = rem >> 3, cg = rem & 7;
        int px = sde ? 97 : 0;
        int byte = (((row * 104 + px) * 64) + cg * 8) ^ ((px & 3) << 4);
        *(ushort4*)(chunk + byte) = (ushort4){0, 0, 0, 0};
    }
    for (int it = tid; it < 2304; it += 256) {
        int g = it & 3;
        int xr = (it >> 2) % 96;
        int row = it / 384;
        int ya = ybase + row - 1;
        bf16x8 v = {0,0,0,0,0,0,0,0};
        if (ya >= 0 && ya < IH) {
            int n = (ya >> lp) * side + (xr >> lp);
            int pyx = ((ya & (P - 1)) << lp) + (xr & (P - 1));
            v = *(const bf16x8*)(yb + (long long)n * dlen + pyx * 64 + g * 8);
        }
        int px = xr + 1;
        int byte = ((((row * 104 + px) * 64) + g * 16)) ^ ((px & 3) << 4);
        *(bf16x8*)(chunk + byte) = v;
    }
}

// ---------------- 3x3 conv via bf16 MFMA implicit GEMM + bias + LeakyReLU
__global__ __launch_bounds__(256) void conv_mfma_kernel(
    const char* __restrict__ img, const unsigned short* __restrict__ Wt,
    const float* __restrict__ bo, float* __restrict__ out)
{
    __shared__ alignas(16) unsigned short in_t[6 * 104 * 32];
    int tid = threadIdx.x;
    int ytile = blockIdx.x, otile = blockIdx.y, bt = blockIdx.z;
    int ybase = ytile * 4, o0 = otile * 64;
    int w = tid >> 6, l = tid & 63;
    int l15 = l & 15, lg = l >> 4;
    int lanebyte = tid * 16, wavebyte = w * 1024;
    const char* ibase = img + (size_t)((bt * 24 + ytile) * 8) * CHUNKB;

    f32x4 acc[4][6];
    #pragma unroll
    for (int mf = 0; mf < 4; mf++)
        #pragma unroll
        for (int nf = 0; nf < 6; nf++)
            acc[mf][nf] = (f32x4){0.f, 0.f, 0.f, 0.f};

    for (int cc = 0; cc < 8; cc++) {
        __syncthreads();
        const char* src = ibase + (size_t)cc * CHUNKB;
        #pragma unroll
        for (int i = 0; i < 9; i++)
            async16((char*)in_t + i * 4096 + wavebyte, src + i * 4096 + lanebyte);
        if (tid < 192)
            async16((char*)in_t + 9 * 4096 + wavebyte, src + 9 * 4096 + lanebyte);
        __syncthreads();

        for (int t = 0; t < 9; t++) {
            int dy = t / 3, dx = t - dy * 3;
            bf16x8 a[4];
            const unsigned short* wp = Wt + ((long long)(t * 8 + cc) * 256 + o0) * 32 + lg * 8;
            #pragma unroll
            for (int mf = 0; mf < 4; mf++)
                a[mf] = *(const bf16x8*)(wp + (mf * 16 + l15) * 32);
            int rowoff = (w + dy) * 104;
            #pragma unroll
            for (int nf = 0; nf < 6; nf++) {
                int px = nf * 16 + l15 + dx;
                int byte = (((rowoff + px) * 64) + lg * 16) ^ ((px & 3) << 4);
                bf16x8 b = *(const bf16x8*)((const char*)in_t + byte);
                #pragma unroll
                for (int mf = 0; mf < 4; mf++)
                    acc[mf][nf] = __builtin_amdgcn_mfma_f32_16x16x32_bf16(a[mf], b, acc[mf][nf], 0, 0, 0);
            }
        }
    }

    int y = ybase + w;
    #pragma unroll
    for (int mf = 0; mf < 4; mf++) {
        #pragma unroll
        for (int reg = 0; reg < 4; reg++) {
            int o = o0 + mf * 16 + lg * 4 + reg;
            float bv = bo[o];
            long long obase = (((long long)bt * CCH + o) * IH + y) * IW;
            #pragma unroll
            for (int nf = 0; nf < 6; nf++) {
                int x = nf * 16 + l15;
                float v = acc[mf][nf][reg] + bv;
                out[obase + x] = v >= 0.f ? v : 0.2f * v;
            }
        }
    }
}

// ---------------- per-head host driver (heads 1-3)
template<int P, int LOGP>
static void run_head(const unsigned short* qw, const unsigned short* kw, const unsigned short* vw,
                     unsigned short* ywb, char* scratch, size_t sbud,
                     int head, int ks, hipStream_t stream)
{
    constexpr int SIDE = 96 / P;
    constexpr int NWIN = SIDE * SIDE;
    constexpr int DLEN = DK * P * P;
    int nw = NWIN, dlen = DLEN;
    float scale = 1.0f / sqrtf((float)dlen);
    int nt = (nw + 63) / 64;
    int tspan = nt * 64;
    dim3 blk(256);

    int btc = BT;
    while (btc > 1 && (size_t)btc * nw * nw * 6 + (ks > 1 ? (size_t)btc * ks * tspan * tspan * 4 : 0) > sbud)
        btc >>= 1;

    float* scores = (float*)scratch;
    unsigned short* pb16 = (unsigned short*)(scratch + (size_t)btc * nw * nw * 4);
    float* partial = (float*)(scratch + (((size_t)btc * nw * nw * 6 + 255) & ~(size_t)255));

    for (int bt0 = 0; bt0 < BT; bt0 += btc) {
        qk_mfma_kernel<<<dim3(nt, nt, btc * ks), blk, 0, stream>>>(qw, kw, scores, partial,
                                                                   nw, dlen, scale, ks, tspan, bt0);
        softmax_kernel<<<dim3(nw, btc), blk, 0, stream>>>(scores, partial, pb16, nw, tspan, ks, scale);
        pv_mfma_kernel<<<dim3(dlen / 64, nt, btc), blk, 0, stream>>>(pb16, vw, ywb, nw, dlen, bt0);
    }
}

extern "C" void kernel_launch(void* const* d_in, const int* in_sizes, int n_in,
                              void* d_out, int out_size, void* d_ws, size_t ws_size,
                              hipStream_t stream) {
    const float* x  = (const float*)d_in[0];
    const float* x1 = (const float*)d_in[1];
    const float* Wq = (const float*)d_in[2];
    const float* bq = (const float*)d_in[3];
    const float* Wk = (const float*)d_in[4];
    const float* bk = (const float*)d_in[5];
    const float* Wv = (const float*)d_in[6];
    const float* bv = (const float*)d_in[7];
    const float* Wo = (const float*)d_in[8];
    const float* bo = (const float*)d_in[9];
    float* out = (float*)d_out;

    unsigned short* xT      = (unsigned short*)d_ws;
    unsigned short* x1T     = xT + NFULL;
    unsigned short* qfull   = x1T + NFULL;
    unsigned short* kfull   = qfull + NFULL;
    unsigned short* vfull   = kfull + NFULL;
    unsigned short* ywb_all = vfull + NFULL;
    unsigned short* kimg    = ywb_all + NFULL;
    unsigned short* vimg    = kimg + WIN;
    unsigned short* Wb = ywb_all;
    char* scratch = (char*)xT;
    unsigned short* Wt = kimg;
    char* img = (char*)xT;

    size_t sbud = (size_t)(8 * WB);

    dim3 blk(256);
    cvtw_kernel<<<192, blk, 0, stream>>>(Wq, Wk, Wv, Wb);
    transpose_cvt_kernel<<<dim3(144, 4, BT), blk, 0, stream>>>(x,  xT);
    transpose_cvt_kernel<<<dim3(144, 4, BT), blk, 0, stream>>>(x1, x1T);

    proj_mfma_kernel<1><<<dim3(144, 1, BT), blk, 0, stream>>>(xT,  Wb, bq, qfull, Wb, bq, qfull,
                                                              nullptr, nullptr);
    proj_mfma_kernel<2><<<dim3(144, 1, BT), blk, 0, stream>>>(x1T, Wb + 65536, bk, kfull,
                                                              Wb + 131072, bv, vfull,
                                                              kimg, nullptr);

    v_image_kernel<<<dim3(36, BT), blk, 0, stream>>>(vfull, vimg);
    flash0_kernel<<<dim3(288), dim3(256), 0, stream>>>(qfull, kimg, vimg, ywb_all);

    run_head<4, 2>(qfull + WIN,     kfull + WIN,     vfull + WIN,     ywb_all + WIN,     scratch, sbud, 1, 1,  stream);
    run_head<8, 3>(qfull + 2 * WIN, kfull + 2 * WIN, vfull + 2 * WIN, ywb_all + 2 * WIN, scratch, sbud, 2, 8,  stream);
    run_head<16,4>(qfull + 3 * WIN, kfull + 3 * WIN, vfull + 3 * WIN, ywb_all + 3 * WIN, scratch, sbud, 3, 64, stream);

    conv_image_kernel<<<dim3(24, 8, BT), blk, 0, stream>>>(ywb_all, img);
    transform_w_kernel<<<(9 * 8 * 256 * 32 + 255) / 256, blk, 0, stream>>>(Wo, Wt);
    conv_mfma_kernel<<<dim3(24, 4, BT), blk, 0, stream>>>(img, Wt, bo, out);
}

// Round 14
// 889.030 us; speedup vs baseline: 1.0654x; 1.0654x over previous
//
#include <hip/hip_runtime.h>
#include <math.h>

#define BT 16
#define CCH 256
#define IH 96
#define IW 96
#define HW (IH*IW)            // 9216
#define DK 64

static const long long WIN   = (long long)BT * HW * DK;   // 9,437,184 elems (one head, all bt)
static const long long NFULL = 4 * WIN;                    // 37,748,736 elems
static const long long WB    = WIN * 2;                    // bytes of one bf16 head buffer
#define CHUNKB 39936          // bytes of one conv LDS-image chunk (6*104*32*2)

typedef __attribute__((ext_vector_type(8))) short bf16x8;
typedef __attribute__((ext_vector_type(4))) float f32x4;

__device__ __forceinline__ unsigned short f2bf(float f) {
    unsigned int x = __float_as_uint(f);
    unsigned int r = (x + 0x7FFFu + ((x >> 16) & 1u)) >> 16;
    return (unsigned short)r;
}

__device__ __forceinline__ void async16(void* lds, const void* g) {
    __builtin_amdgcn_global_load_lds(
        (const __attribute__((address_space(1))) unsigned int*)g,
        (__attribute__((address_space(3))) unsigned int*)lds, 16, 0, 0);
}

// ---------------- transpose+convert: x[bt][c][hw] fp32 -> xT[bt][hw][c] bf16
__global__ __launch_bounds__(256) void transpose_cvt_kernel(const float* __restrict__ x,
    unsigned short* __restrict__ xT)
{
    __shared__ float Ls[64][65];
    int tid = threadIdx.x;
    int p0 = blockIdx.x * 64;
    int c0 = blockIdx.y * 64;
    int bt = blockIdx.z;
    int px4 = (tid & 15) * 4, chb = tid >> 4;
    const float* xb = x + ((long long)(bt * CCH + c0) * HW) + p0;
    #pragma unroll
    for (int it = 0; it < 4; it++) {
        int ch = chb + it * 16;
        float4 v = *(const float4*)(xb + (long long)ch * HW + px4);
        Ls[px4 + 0][ch] = v.x;
        Ls[px4 + 1][ch] = v.y;
        Ls[px4 + 2][ch] = v.z;
        Ls[px4 + 3][ch] = v.w;
    }
    __syncthreads();
    int px = tid >> 2, cg = (tid & 3) * 16;
    unsigned short* dst = xT + ((long long)bt * HW + p0 + px) * CCH + c0 + cg;
    #pragma unroll
    for (int half = 0; half < 2; half++) {
        ushort4 a, b;
        a.x = f2bf(Ls[px][cg + half * 8 + 0]);
        a.y = f2bf(Ls[px][cg + half * 8 + 1]);
        a.z = f2bf(Ls[px][cg + half * 8 + 2]);
        a.w = f2bf(Ls[px][cg + half * 8 + 3]);
        b.x = f2bf(Ls[px][cg + half * 8 + 4]);
        b.y = f2bf(Ls[px][cg + half * 8 + 5]);
        b.z = f2bf(Ls[px][cg + half * 8 + 6]);
        b.w = f2bf(Ls[px][cg + half * 8 + 7]);
        *(ushort4*)(dst + half * 8)     = a;
        *(ushort4*)(dst + half * 8 + 4) = b;
    }
}

// ---------------- Wq/Wk/Wv fp32 -> bf16 (same [o][c] layout), packed [3][256][256]
__global__ __launch_bounds__(256) void cvtw_kernel(const float* __restrict__ Wq,
    const float* __restrict__ Wk, const float* __restrict__ Wv,
    unsigned short* __restrict__ Wb)
{
    int idx = blockIdx.x * 256 + threadIdx.x;
    if (idx >= 3 * 16384) return;
    const float* src = idx < 16384 ? Wq : (idx < 32768 ? Wk : Wv);
    int off = (idx & 16383) * 4;
    float4 v = *(const float4*)(src + off);
    ushort4 u = {f2bf(v.x), f2bf(v.y), f2bf(v.z), f2bf(v.w)};
    *(ushort4*)(Wb + (long long)idx * 4) = u;
}

// ---------------- fused 1x1-conv projections via bf16 MFMA (bf16 inputs)
template<int NPASS>
__global__ __launch_bounds__(256) void proj_mfma_kernel(
    const unsigned short* __restrict__ xT,
    const unsigned short* __restrict__ Wb0, const float* __restrict__ b0, unsigned short* __restrict__ o0p,
    const unsigned short* __restrict__ Wb1, const float* __restrict__ b1, unsigned short* __restrict__ o1p,
    unsigned short* __restrict__ i0p, unsigned short* __restrict__ i1p)
{
    __shared__ alignas(16) unsigned short Xs[64 * 256];
    __shared__ alignas(16) unsigned short Ws[256 * 64];
    int tid = threadIdx.x;
    int p0 = blockIdx.x * 64;
    int bt = blockIdx.z;
    int w = tid >> 6, l = tid & 63, l15 = l & 15, lg = l >> 4;

    {
        const unsigned short* xb = xT + ((long long)bt * HW + p0) * CCH;
        #pragma unroll
        for (int it = 0; it < 8; it++) {
            int flat = tid + it * 256;
            int px = flat >> 5, cg = flat & 31;
            bf16x8 v = *(const bf16x8*)(xb + (long long)px * CCH + cg * 8);
            *(bf16x8*)((char*)Xs + px * 512 + ((cg ^ (px & 31)) << 4)) = v;
        }
    }

    for (int pass = 0; pass < NPASS; pass++) {
        const unsigned short* W = pass ? Wb1 : Wb0;
        const float* bias = pass ? b1 : b0;
        unsigned short* outp = pass ? o1p : o0p;
        unsigned short* img = pass ? i1p : i0p;

        f32x4 acc[4][4];
        #pragma unroll
        for (int i = 0; i < 4; i++)
            #pragma unroll
            for (int j = 0; j < 4; j++) acc[i][j] = (f32x4){0.f, 0.f, 0.f, 0.f};

        for (int kc = 0; kc < CCH; kc += 64) {
            __syncthreads();
            #pragma unroll
            for (int it = 0; it < 8; it++) {
                int flat = tid + it * 256;
                int o = flat >> 3, kg = flat & 7;
                bf16x8 v = *(const bf16x8*)(W + o * 256 + kc + kg * 8);
                *(bf16x8*)((char*)Ws + o * 128 + ((kg ^ (o & 7)) << 4)) = v;
            }
            __syncthreads();
            #pragma unroll
            for (int kst = 0; kst < 2; kst++) {
                bf16x8 a[4], b[4];
                #pragma unroll
                for (int mf = 0; mf < 4; mf++) {
                    int m = w * 64 + mf * 16 + l15;
                    int uu = (kst * 4 + lg) ^ (m & 7);
                    a[mf] = *(const bf16x8*)((const char*)Ws + m * 128 + (uu << 4));
                }
                #pragma unroll
                for (int nf = 0; nf < 4; nf++) {
                    int px = nf * 16 + l15;
                    int ug = (kc >> 3) + kst * 4 + lg;
                    b[nf] = *(const bf16x8*)((const char*)Xs + px * 512 + ((ug ^ (px & 31)) << 4));
                }
                #pragma unroll
                for (int mf = 0; mf < 4; mf++)
                    #pragma unroll
                    for (int nf = 0; nf < 4; nf++)
                        acc[mf][nf] = __builtin_amdgcn_mfma_f32_16x16x32_bf16(a[mf], b[nf], acc[mf][nf], 0, 0, 0);
            }
        }

        __syncthreads();
        #pragma unroll
        for (int mf = 0; mf < 4; mf++) {
            int ch0 = w * 64 + mf * 16 + lg * 4;
            float4 bv = *(const float4*)(bias + ch0);
            #pragma unroll
            for (int nf = 0; nf < 4; nf++) {
                int px = nf * 16 + l15;
                ushort4 u4 = {f2bf(acc[mf][nf][0] + bv.x), f2bf(acc[mf][nf][1] + bv.y),
                              f2bf(acc[mf][nf][2] + bv.z), f2bf(acc[mf][nf][3] + bv.w)};
                int uu = (ch0 >> 3) ^ (px & 31);
                *(ushort4*)((char*)Ws + px * 512 + (uu << 4) + ((ch0 >> 2) & 1) * 8) = u4;
            }
        }
        __syncthreads();
        {
            int cg = tid & 31;
            int h = cg >> 3, lp = h + 1, P = 2 << h;
            int side = 96 >> lp;
            int nwin = side * side;
            long long dlen = (long long)64 << (2 * lp);
            unsigned short* dst = outp + (long long)h * WIN + (long long)bt * nwin * dlen + (cg & 7) * 8;
            #pragma unroll
            for (int it = 0; it < 8; it++) {
                int pxl = it * 8 + (tid >> 5);
                int p = p0 + pxl;
                int y = p / 96, xx = p - y * 96;
                int n = (y >> lp) * side + (xx >> lp);
                int pyx = ((y & (P - 1)) << lp) + (xx & (P - 1));
                int uu = cg ^ (pxl & 31);
                bf16x8 v = *(const bf16x8*)((const char*)Ws + pxl * 512 + (uu << 4));
                if (img != nullptr && h == 0) {
                    int mt = n >> 6, row = n & 63;
                    int kg = pyx * 8 + (cg & 7);
                    int u = (kg & 24) | ((kg ^ row) & 7);
                    *(bf16x8*)((char*)img + (((long long)(bt * 36 + mt)) << 15) + row * 512 + (u << 4)) = v;
                } else {
                    *(bf16x8*)(dst + (long long)n * dlen + (long long)pyx * 64) = v;
                }
            }
        }
    }
}

// ---------------- head0 V -> V^T LDS-image tiles in global
__global__ __launch_bounds__(256) void v_image_kernel(
    const unsigned short* __restrict__ vf, unsigned short* __restrict__ vimg)
{
    __shared__ alignas(16) unsigned short Vt[64 * 256];
    int tid = threadIdx.x;
    int mt = blockIdx.x;   // 0..35
    int bt = blockIdx.y;
    const unsigned short* vb = vf + ((long long)bt * 2304 + mt * 64) * 256;
    unsigned short* vi = vimg + (long long)(bt * 36 + mt) * (64 * 256);

    int du = tid & 15, mu = tid >> 4;
    #pragma unroll
    for (int dblk = 0; dblk < 4; dblk++) {
        ushort4 vv[4];
        #pragma unroll
        for (int i = 0; i < 4; i++)
            vv[i] = *(const ushort4*)(vb + (long long)(mu * 4 + i) * 256 + (dblk * 16 + du) * 4);
        #pragma unroll
        for (int j = 0; j < 4; j++) {
            int d = (dblk * 16 + du) * 4 + j;
            ushort4 tj;
            tj.x = ((const unsigned short*)&vv[0])[j];
            tj.y = ((const unsigned short*)&vv[1])[j];
            tj.z = ((const unsigned short*)&vv[2])[j];
            tj.w = ((const unsigned short*)&vv[3])[j];
            int slot = (((mu >> 3) * 4 + (mu & 3)) ^ (d & 7));
            *(ushort4*)((char*)Vt + d * 128 + (slot << 4) + ((mu & 4) ? 8 : 0)) = tj;
        }
    }
    __syncthreads();
    #pragma unroll
    for (int it = 0; it < 8; it++) {
        int c = tid + it * 256;
        *(bf16x8*)((char*)vi + c * 16) = *(const bf16x8*)((const char*)Vt + c * 16);
    }
}

// ---------------- head 0 flash attention: 512 thr, QBLK=128, image staging (r12 proven)
__global__ __launch_bounds__(512, 4) void flash0_kernel(
    const unsigned short* __restrict__ q, const unsigned short* __restrict__ kimg,
    const unsigned short* __restrict__ vimg, unsigned short* __restrict__ o)
{
    constexpr int NW = 2304, D = 256;
    __shared__ alignas(16) unsigned short Kb[64 * 256];   // 32KB K tile image
    __shared__ alignas(16) unsigned short Vb[64 * 256];   // 32KB V^T tile image
    int tid = threadIdx.x;
    int w = tid >> 6, l = tid & 63, l15 = l & 15, lg = l >> 4;
    int bid = blockIdx.x;
    int xcd = bid & 7, r = bid >> 3;          // bt<->XCD binding for L2 locality
    int bt = 2 * xcd + (r >= 18 ? 1 : 0);
    int qt = (r >= 18) ? r - 18 : r;
    int q0 = qt * 128;
    const unsigned short* qb = q + ((long long)bt * NW + q0) * D;
    const char* kti = (const char*)(kimg + (long long)bt * 36 * (64 * 256));
    const char* vti = (const char*)(vimg + (long long)bt * 36 * (64 * 256));
    const float scale = 1.0f / 16.0f;

    bf16x8 qf[8];
    #pragma unroll
    for (int i = 0; i < 8; i++)
        qf[i] = *(const bf16x8*)(qb + (long long)(w * 16 + l15) * D + i * 32 + lg * 8);

    f32x4 Oacc[16];
    #pragma unroll
    for (int i = 0; i < 16; i++) Oacc[i] = (f32x4){0.f, 0.f, 0.f, 0.f};
    float mrow = -3e38f, srow = 0.f;   // per-lane q = l15 (replicated over lg)

    int lanebyte = tid * 16;
    int wavebyte = w * 1024;

    for (int mt = 0; mt < 36; mt++) {
        __syncthreads();
        const char* ks = kti + (long long)mt * 32768;
        const char* vs = vti + (long long)mt * 32768;
        #pragma unroll
        for (int i = 0; i < 4; i++) {
            async16((char*)Kb + i * 8192 + wavebyte, ks + i * 8192 + lanebyte);
            async16((char*)Vb + i * 8192 + wavebyte, vs + i * 8192 + lanebyte);
        }
        __syncthreads();
        // ---- swapped QK^T: S^T[kv][q], A = K, B = Q regs
        f32x4 s[4];
        #pragma unroll
        for (int nf = 0; nf < 4; nf++) s[nf] = (f32x4){0.f, 0.f, 0.f, 0.f};
        #pragma unroll
        for (int i = 0; i < 8; i++) {
            int kgu = i * 4 + lg;
            #pragma unroll
            for (int nf = 0; nf < 4; nf++) {
                int arow = nf * 16 + l15;
                int u = (kgu & 24) | ((kgu ^ arow) & 7);
                bf16x8 a = *(const bf16x8*)((const char*)Kb + arow * 512 + (u << 4));
                s[nf] = __builtin_amdgcn_mfma_f32_16x16x32_bf16(a, qf[i], s[nf], 0, 0, 0);
            }
        }
        // ---- online softmax, per-lane row q = l15
        float pm = -3e38f;
        #pragma unroll
        for (int nf = 0; nf < 4; nf++)
            #pragma unroll
            for (int rg = 0; rg < 4; rg++) { s[nf][rg] *= scale; pm = fmaxf(pm, s[nf][rg]); }
        pm = fmaxf(pm, __shfl_xor(pm, 16, 64));
        pm = fmaxf(pm, __shfl_xor(pm, 32, 64));
        if (__any(pm > mrow)) {
            float mnew = fmaxf(mrow, pm);
            float corr = __expf(mrow - mnew);
            mrow = mnew; srow *= corr;
            float cO[4];
            #pragma unroll
            for (int rg = 0; rg < 4; rg++) cO[rg] = __shfl(corr, (l & 48) | (lg * 4 + rg), 64);
            #pragma unroll
            for (int nf2 = 0; nf2 < 16; nf2++)
                #pragma unroll
                for (int rg = 0; rg < 4; rg++) Oacc[nf2][rg] *= cO[rg];
        }
        float ps = 0.f;
        #pragma unroll
        for (int nf = 0; nf < 4; nf++)
            #pragma unroll
            for (int rg = 0; rg < 4; rg++) { s[nf][rg] = __expf(s[nf][rg] - mrow); ps += s[nf][rg]; }
        ps += __shfl_xor(ps, 16, 64);
        ps += __shfl_xor(ps, 32, 64);
        srow += ps;
        bf16x8 pa[2];
        #pragma unroll
        for (int sl = 0; sl < 2; sl++) {
            pa[sl][0] = (short)f2bf(s[sl * 2][0]);
            pa[sl][1] = (short)f2bf(s[sl * 2][1]);
            pa[sl][2] = (short)f2bf(s[sl * 2][2]);
            pa[sl][3] = (short)f2bf(s[sl * 2][3]);
            pa[sl][4] = (short)f2bf(s[sl * 2 + 1][0]);
            pa[sl][5] = (short)f2bf(s[sl * 2 + 1][1]);
            pa[sl][6] = (short)f2bf(s[sl * 2 + 1][2]);
            pa[sl][7] = (short)f2bf(s[sl * 2 + 1][3]);
        }
        // ---- PV: A = P regs (row = q = l15), B = V^T image
        #pragma unroll
        for (int nf2 = 0; nf2 < 16; nf2++) {
            int d = nf2 * 16 + l15;
            #pragma unroll
            for (int kc = 0; kc < 2; kc++) {
                int slot = (kc * 4 + lg) ^ (d & 7);
                bf16x8 b = *(const bf16x8*)((const char*)Vb + d * 128 + (slot << 4));
                Oacc[nf2] = __builtin_amdgcn_mfma_f32_16x16x32_bf16(pa[kc], b, Oacc[nf2], 0, 0, 0);
            }
        }
    }
    float inv = 1.f / srow;
    float iO[4];
    #pragma unroll
    for (int rg = 0; rg < 4; rg++) iO[rg] = __shfl(inv, (l & 48) | (lg * 4 + rg), 64);
    unsigned short* ob = o + ((long long)bt * NW + q0) * D;
    #pragma unroll
    for (int rg = 0; rg < 4; rg++) {
        int qr = w * 16 + lg * 4 + rg;
        #pragma unroll
        for (int nf2 = 0; nf2 < 16; nf2++) {
            int dd = nf2 * 16 + l15;
            ob[(long long)qr * D + dd] = f2bf(Oacc[nf2][rg] * iO[rg]);
        }
    }
}

// ---------------- QK^T via bf16 MFMA, 64x64 tile, optional split-K (heads 1-3)
__global__ __launch_bounds__(256) void qk_mfma_kernel(const unsigned short* __restrict__ qw,
    const unsigned short* __restrict__ kw, float* __restrict__ scores,
    float* __restrict__ partial, int nw, int dlen, float scale, int ksplit,
    int tspan, int bt0)
{
    __shared__ alignas(16) unsigned short Qs[64 * 64];
    __shared__ alignas(16) unsigned short Ks[64 * 64];
    int tid = threadIdx.x;
    int m0 = blockIdx.x * 64, n0 = blockIdx.y * 64;
    int btl = blockIdx.z / ksplit;
    int kidx = blockIdx.z - btl * ksplit;
    int bt = bt0 + btl;
    int dchunk = dlen / ksplit;
    long long kbase = (long long)kidx * dchunk;
    int w = tid >> 6, l = tid & 63, l15 = l & 15, lg = l >> 4;
    f32x4 acc[4];
    #pragma unroll
    for (int nf = 0; nf < 4; nf++) acc[nf] = (f32x4){0.f, 0.f, 0.f, 0.f};

    const unsigned short* qb = qw + ((long long)bt * nw + n0) * dlen + kbase;
    const unsigned short* kb = kw + ((long long)bt * nw + m0) * dlen + kbase;
    int qrows = nw - n0; if (qrows > 64) qrows = 64;
    int krows = nw - m0; if (krows > 64) krows = 64;
    int arow = w * 16 + l15;

    for (int kc = 0; kc < dchunk; kc += 64) {
        if (kc) __syncthreads();
        #pragma unroll
        for (int i = 0; i < 2; i++) {
            int c = tid + i * 256;
            int row = c >> 3, kg = c & 7;
            int kgs = (kg ^ (row & 7)) * 8;
            bf16x8 qv = {0,0,0,0,0,0,0,0};
            bf16x8 kv = {0,0,0,0,0,0,0,0};
            if (row < qrows) qv = *(const bf16x8*)(qb + (long long)row * dlen + kc + kg * 8);
            if (row < krows) kv = *(const bf16x8*)(kb + (long long)row * dlen + kc + kg * 8);
            *(bf16x8*)(Qs + row * 64 + kgs) = qv;
            *(bf16x8*)(Ks + row * 64 + kgs) = kv;
        }
        __syncthreads();
        #pragma unroll
        for (int k0 = 0; k0 < 64; k0 += 32) {
            int kg = (k0 >> 3) + lg;
            bf16x8 a = *(const bf16x8*)(Qs + arow * 64 + (kg ^ (arow & 7)) * 8);
            #pragma unroll
            for (int nf = 0; nf < 4; nf++) {
                int col = nf * 16 + l15;
                bf16x8 b = *(const bf16x8*)(Ks + col * 64 + (kg ^ (col & 7)) * 8);
                acc[nf] = __builtin_amdgcn_mfma_f32_16x16x32_bf16(a, b, acc[nf], 0, 0, 0);
            }
        }
    }

    if (ksplit == 1) {
        #pragma unroll
        for (int nf = 0; nf < 4; nf++) {
            int c = m0 + nf * 16 + l15;
            #pragma unroll
            for (int reg = 0; reg < 4; reg++) {
                int r = n0 + w * 16 + lg * 4 + reg;
                if (r < nw && c < nw)
                    scores[((long long)btl * nw + r) * nw + c] = acc[nf][reg] * scale;
            }
        }
    } else {
        #pragma unroll
        for (int nf = 0; nf < 4; nf++) {
            int c = m0 + nf * 16 + l15;
            #pragma unroll
            for (int reg = 0; reg < 4; reg++) {
                int r = n0 + w * 16 + lg * 4 + reg;
                partial[(((long long)btl * ksplit + kidx) * tspan + r) * tspan + c] = acc[nf][reg];
            }
        }
    }
}

// ---------------- row softmax (with fused split-K reduce): scores/partial in, bf16 P out
__global__ __launch_bounds__(256) void softmax_kernel(const float* __restrict__ scores,
    const float* __restrict__ partial, unsigned short* __restrict__ pb16,
    int nw, int tspan, int ksplit, float scale)
{
    __shared__ float red[8];
    int n = blockIdx.x, btl = blockIdx.y;
    const float* row = scores + ((long long)btl * nw + n) * nw;
    unsigned short* prow = pb16 + ((long long)btl * nw + n) * nw;
    int tid = threadIdx.x;
    float vals[9];
    float lmax = -3e38f;
    #pragma unroll
    for (int it = 0; it < 9; it++) {
        int m = tid + it * 256;
        if (m < nw) {
            float v;
            if (ksplit == 1) {
                v = row[m];
            } else {
                float s = 0.f;
                for (int k = 0; k < ksplit; k++)
                    s += partial[(((long long)btl * ksplit + k) * tspan + n) * tspan + m];
                v = s * scale;
            }
            vals[it] = v; lmax = fmaxf(lmax, v);
        } else vals[it] = -3e38f;
    }
    #pragma unroll
    for (int o = 32; o > 0; o >>= 1) lmax = fmaxf(lmax, __shfl_down(lmax, o, 64));
    if ((tid & 63) == 0) red[tid >> 6] = lmax;
    __syncthreads();
    float rmax = fmaxf(fmaxf(red[0], red[1]), fmaxf(red[2], red[3]));
    __syncthreads();
    float lsum = 0.f;
    #pragma unroll
    for (int it = 0; it < 9; it++) {
        int m = tid + it * 256;
        if (m < nw) { vals[it] = __expf(vals[it] - rmax); lsum += vals[it]; }
    }
    #pragma unroll
    for (int o = 32; o > 0; o >>= 1) lsum += __shfl_down(lsum, o, 64);
    if ((tid & 63) == 0) red[tid >> 6] = lsum;
    __syncthreads();
    float rsum = red[0] + red[1] + red[2] + red[3];
    float inv = 1.f / rsum;
    #pragma unroll
    for (int it = 0; it < 9; it++) {
        int m = tid + it * 256;
        if (m < nw) prow[m] = f2bf(vals[it] * inv);
    }
}

// ---------------- P @ V via bf16 MFMA; 64(n) x 64(d) tile, bf16 output
__global__ __launch_bounds__(256) void pv_mfma_kernel(const unsigned short* __restrict__ p,
    const unsigned short* __restrict__ vw, unsigned short* __restrict__ yw, int nw, int dlen, int bt0)
{
    __shared__ alignas(16) unsigned short Ps[64 * 64];
    __shared__ alignas(16) unsigned short Vt[64 * 64];
    int tid = threadIdx.x;
    int d0 = blockIdx.x * 64, n0 = blockIdx.y * 64;
    int btl = blockIdx.z;
    int bt = bt0 + btl;
    int w = tid >> 6, l = tid & 63, l15 = l & 15, lg = l >> 4;
    f32x4 acc[4];
    #pragma unroll
    for (int nf = 0; nf < 4; nf++) acc[nf] = (f32x4){0.f, 0.f, 0.f, 0.f};

    const unsigned short* pb = p + ((long long)btl * nw + n0) * nw;
    const unsigned short* vb = vw + (long long)bt * nw * dlen + d0;
    int prows = nw - n0; if (prows > 64) prows = 64;
    int arow = w * 16 + l15;
    int du = tid & 15, mu = tid >> 4;

    for (int mc = 0; mc < nw; mc += 64) {
        if (mc) __syncthreads();
        int mrem = nw - mc;
        #pragma unroll
        for (int i = 0; i < 2; i++) {
            int c = tid + i * 256;
            int row = c >> 3, kg = c & 7;
            bf16x8 v = {0,0,0,0,0,0,0,0};
            if (row < prows) {
                int mb = kg * 8;
                if (mb + 8 <= mrem) v = *(const bf16x8*)(pb + (long long)row * nw + mc + mb);
                else if (mb < mrem) {
                    for (int e = 0; e < mrem - mb; e++)
                        v[e] = (short)pb[(long long)row * nw + mc + mb + e];
                }
            }
            *(bf16x8*)(Ps + row * 64 + (kg ^ (row & 7)) * 8) = v;
        }
        {
            ushort4 vv[4];
            #pragma unroll
            for (int i = 0; i < 4; i++) {
                int m = mc + mu * 4 + i;
                if (m < nw) vv[i] = *(const ushort4*)(vb + (long long)m * dlen + du * 4);
                else vv[i] = (ushort4){0, 0, 0, 0};
            }
            #pragma unroll
            for (int j = 0; j < 4; j++) {
                int d = du * 4 + j;
                int byte = d * 128 + (((mu >> 1) ^ (d & 7)) * 16) + (mu & 1) * 8;
                ushort4 tj;
                tj.x = ((const unsigned short*)&vv[0])[j];
                tj.y = ((const unsigned short*)&vv[1])[j];
                tj.z = ((const unsigned short*)&vv[2])[j];
                tj.w = ((const unsigned short*)&vv[3])[j];
                *(ushort4*)((char*)Vt + byte) = tj;
            }
        }
        __syncthreads();
        #pragma unroll
        for (int k0 = 0; k0 < 64; k0 += 32) {
            int kg = (k0 >> 3) + lg;
            bf16x8 a = *(const bf16x8*)(Ps + arow * 64 + (kg ^ (arow & 7)) * 8);
            #pragma unroll
            for (int nf = 0; nf < 4; nf++) {
                int col = nf * 16 + l15;
                bf16x8 b = *(const bf16x8*)(Vt + col * 64 + (kg ^ (col & 7)) * 8);
                acc[nf] = __builtin_amdgcn_mfma_f32_16x16x32_bf16(a, b, acc[nf], 0, 0, 0);
            }
        }
    }

    #pragma unroll
    for (int nf = 0; nf < 4; nf++) {
        int d = d0 + nf * 16 + l15;
        #pragma unroll
        for (int reg = 0; reg < 4; reg++) {
            int n = n0 + w * 16 + lg * 4 + reg;
            if (n < nw)
                yw[((long long)bt * nw + n) * dlen + d] = f2bf(acc[nf][reg]);
        }
    }
}

// ---------------- Wo fp32 [o][c][3][3] -> bf16 Wt[t][cc][o][cl]
__global__ __launch_bounds__(256) void transform_w_kernel(const float* __restrict__ Wo,
    unsigned short* __restrict__ Wt)
{
    int idx = blockIdx.x * 256 + threadIdx.x;
    if (idx >= 9 * 8 * 256 * 32) return;
    int cl = idx & 31;
    int o  = (idx >> 5) & 255;
    int cc = (idx >> 13) & 7;
    int t  = idx >> 16;
    int dy = t / 3, dx = t - dy * 3;
    int c = cc * 32 + cl;
    Wt[idx] = f2bf(Wo[((long long)(o * CCH + c) * 3 + dy) * 3 + dx]);
}

// ---------------- conv input image: per (ytile, cc, bt), byte-exact LDS tile in global
__global__ __launch_bounds__(256) void conv_image_kernel(
    const unsigned short* __restrict__ ywb_all, char* __restrict__ img)
{
    int tid = threadIdx.x;
    int ytile = blockIdx.x, cc = blockIdx.y, bt = blockIdx.z;
    int ybase = ytile * 4;
    char* chunk = img + (size_t)(((bt * 24 + ytile) * 8) + cc) * CHUNKB;
    int h = cc >> 1;
    int lp = h + 1, P = 2 << h;
    int side = 96 >> lp;
    int nwin = side * side;
    long long dlen = 64LL << (2 * lp);
    const unsigned short* yb = ywb_all + (long long)h * WIN
                             + (long long)bt * nwin * dlen + (cc & 1) * 32;
    for (int it = tid; it < 96; it += 256) {
        int sde = it / 48, rem = it - sde * 48;
        int row = rem >> 3, cg = rem & 7;
        int px = sde ? 97 : 0;
        int byte = (((row * 104 + px) * 64) + cg * 8) ^ ((px & 3) << 4);
        *(ushort4*)(chunk + byte) = (ushort4){0, 0, 0, 0};
    }
    for (int it = tid; it < 2304; it += 256) {
        int g = it & 3;
        int xr = (it >> 2) % 96;
        int row = it / 384;
        int ya = ybase + row - 1;
        bf16x8 v = {0,0,0,0,0,0,0,0};
        if (ya >= 0 && ya < IH) {
            int n = (ya >> lp) * side + (xr >> lp);
            int pyx = ((ya & (P - 1)) << lp) + (xr & (P - 1));
            v = *(const bf16x8*)(yb + (long long)n * dlen + pyx * 64 + g * 8);
        }
        int px = xr + 1;
        int byte = ((((row * 104 + px) * 64) + g * 16)) ^ ((px & 3) << 4);
        *(bf16x8*)(chunk + byte) = v;
    }
}

// ---------------- 3x3 conv via bf16 MFMA implicit GEMM + bias + LeakyReLU
__global__ __launch_bounds__(256) void conv_mfma_kernel(
    const char* __restrict__ img, const unsigned short* __restrict__ Wt,
    const float* __restrict__ bo, float* __restrict__ out)
{
    __shared__ alignas(16) unsigned short in_t[6 * 104 * 32];
    int tid = threadIdx.x;
    int ytile = blockIdx.x, otile = blockIdx.y, bt = blockIdx.z;
    int ybase = ytile * 4, o0 = otile * 64;
    int w = tid >> 6, l = tid & 63;
    int l15 = l & 15, lg = l >> 4;
    int lanebyte = tid * 16, wavebyte = w * 1024;
    const char* ibase = img + (size_t)((bt * 24 + ytile) * 8) * CHUNKB;

    f32x4 acc[4][6];
    #pragma unroll
    for (int mf = 0; mf < 4; mf++)
        #pragma unroll
        for (int nf = 0; nf < 6; nf++)
            acc[mf][nf] = (f32x4){0.f, 0.f, 0.f, 0.f};

    for (int cc = 0; cc < 8; cc++) {
        __syncthreads();
        const char* src = ibase + (size_t)cc * CHUNKB;
        #pragma unroll
        for (int i = 0; i < 9; i++)
            async16((char*)in_t + i * 4096 + wavebyte, src + i * 4096 + lanebyte);
        if (tid < 192)
            async16((char*)in_t + 9 * 4096 + wavebyte, src + 9 * 4096 + lanebyte);
        __syncthreads();

        for (int t = 0; t < 9; t++) {
            int dy = t / 3, dx = t - dy * 3;
            bf16x8 a[4];
            const unsigned short* wp = Wt + ((long long)(t * 8 + cc) * 256 + o0) * 32 + lg * 8;
            #pragma unroll
            for (int mf = 0; mf < 4; mf++)
                a[mf] = *(const bf16x8*)(wp + (mf * 16 + l15) * 32);
            int rowoff = (w + dy) * 104;
            #pragma unroll
            for (int nf = 0; nf < 6; nf++) {
                int px = nf * 16 + l15 + dx;
                int byte = (((rowoff + px) * 64) + lg * 16) ^ ((px & 3) << 4);
                bf16x8 b = *(const bf16x8*)((const char*)in_t + byte);
                #pragma unroll
                for (int mf = 0; mf < 4; mf++)
                    acc[mf][nf] = __builtin_amdgcn_mfma_f32_16x16x32_bf16(a[mf], b, acc[mf][nf], 0, 0, 0);
            }
        }
    }

    int y = ybase + w;
    #pragma unroll
    for (int mf = 0; mf < 4; mf++) {
        #pragma unroll
        for (int reg = 0; reg < 4; reg++) {
            int o = o0 + mf * 16 + lg * 4 + reg;
            float bv = bo[o];
            long long obase = (((long long)bt * CCH + o) * IH + y) * IW;
            #pragma unroll
            for (int nf = 0; nf < 6; nf++) {
                int x = nf * 16 + l15;
                float v = acc[mf][nf][reg] + bv;
                out[obase + x] = v >= 0.f ? v : 0.2f * v;
            }
        }
    }
}

// ---------------- per-head host driver (heads 1-3)
template<int P, int LOGP>
static void run_head(const unsigned short* qw, const unsigned short* kw, const unsigned short* vw,
                     unsigned short* ywb, char* scratch, size_t sbud,
                     int head, int ks, hipStream_t stream)
{
    constexpr int SIDE = 96 / P;
    constexpr int NWIN = SIDE * SIDE;
    constexpr int DLEN = DK * P * P;
    int nw = NWIN, dlen = DLEN;
    float scale = 1.0f / sqrtf((float)dlen);
    int nt = (nw + 63) / 64;
    int tspan = nt * 64;
    dim3 blk(256);

    int btc = BT;
    while (btc > 1 && (size_t)btc * nw * nw * 6 + (ks > 1 ? (size_t)btc * ks * tspan * tspan * 4 : 0) > sbud)
        btc >>= 1;

    float* scores = (float*)scratch;
    unsigned short* pb16 = (unsigned short*)(scratch + (size_t)btc * nw * nw * 4);
    float* partial = (float*)(scratch + (((size_t)btc * nw * nw * 6 + 255) & ~(size_t)255));

    for (int bt0 = 0; bt0 < BT; bt0 += btc) {
        qk_mfma_kernel<<<dim3(nt, nt, btc * ks), blk, 0, stream>>>(qw, kw, scores, partial,
                                                                   nw, dlen, scale, ks, tspan, bt0);
        softmax_kernel<<<dim3(nw, btc), blk, 0, stream>>>(scores, partial, pb16, nw, tspan, ks, scale);
        pv_mfma_kernel<<<dim3(dlen / 64, nt, btc), blk, 0, stream>>>(pb16, vw, ywb, nw, dlen, bt0);
    }
}

extern "C" void kernel_launch(void* const* d_in, const int* in_sizes, int n_in,
                              void* d_out, int out_size, void* d_ws, size_t ws_size,
                              hipStream_t stream) {
    const float* x  = (const float*)d_in[0];
    const float* x1 = (const float*)d_in[1];
    const float* Wq = (const float*)d_in[2];
    const float* bq = (const float*)d_in[3];
    const float* Wk = (const float*)d_in[4];
    const float* bk = (const float*)d_in[5];
    const float* Wv = (const float*)d_in[6];
    const float* bv = (const float*)d_in[7];
    const float* Wo = (const float*)d_in[8];
    const float* bo = (const float*)d_in[9];
    float* out = (float*)d_out;

    unsigned short* xT      = (unsigned short*)d_ws;
    unsigned short* x1T     = xT + NFULL;
    unsigned short* qfull   = x1T + NFULL;
    unsigned short* kfull   = qfull + NFULL;
    unsigned short* vfull   = kfull + NFULL;
    unsigned short* ywb_all = vfull + NFULL;
    unsigned short* kimg    = ywb_all + NFULL;
    unsigned short* vimg    = kimg + WIN;
    unsigned short* Wb = ywb_all;
    char* scratch = (char*)xT;
    unsigned short* Wt = kimg;
    char* img = (char*)xT;

    size_t sbud = (size_t)(8 * WB);

    dim3 blk(256);
    cvtw_kernel<<<192, blk, 0, stream>>>(Wq, Wk, Wv, Wb);
    transpose_cvt_kernel<<<dim3(144, 4, BT), blk, 0, stream>>>(x,  xT);
    transpose_cvt_kernel<<<dim3(144, 4, BT), blk, 0, stream>>>(x1, x1T);

    proj_mfma_kernel<1><<<dim3(144, 1, BT), blk, 0, stream>>>(xT,  Wb, bq, qfull, Wb, bq, qfull,
                                                              nullptr, nullptr);
    proj_mfma_kernel<2><<<dim3(144, 1, BT), blk, 0, stream>>>(x1T, Wb + 65536, bk, kfull,
                                                              Wb + 131072, bv, vfull,
                                                              kimg, nullptr);

    v_image_kernel<<<dim3(36, BT), blk, 0, stream>>>(vfull, vimg);
    flash0_kernel<<<dim3(288), dim3(512), 0, stream>>>(qfull, kimg, vimg, ywb_all);

    run_head<4, 2>(qfull + WIN,     kfull + WIN,     vfull + WIN,     ywb_all + WIN,     scratch, sbud, 1, 1,  stream);
    run_head<8, 3>(qfull + 2 * WIN, kfull + 2 * WIN, vfull + 2 * WIN, ywb_all + 2 * WIN, scratch, sbud, 2, 8,  stream);
    run_head<16,4>(qfull + 3 * WIN, kfull + 3 * WIN, vfull + 3 * WIN, ywb_all + 3 * WIN, scratch, sbud, 3, 64, stream);

    conv_image_kernel<<<dim3(24, 8, BT), blk, 0, stream>>>(ywb_all, img);
    transform_w_kernel<<<(9 * 8 * 256 * 32 + 255) / 256, blk, 0, stream>>>(Wo, Wt);
    conv_mfma_kernel<<<dim3(24, 4, BT), blk, 0, stream>>>(img, Wt, bo, out);
}